// Round 18
// baseline (161.254 us; speedup 1.0000x reference)
//
#include <hip/hip_runtime.h>

// CapsNet forward — fully fused.
// packAll: w2 -> MFMA B-fragments + W_route -> f16 c-pairs
// capsnet_fused (1 sample/block, 320 thr, 65KB LDS -> 2 blocks/CU):
//   conv1 fp32 (R16) -> sOut[400][20]f16 -> conv2 MFMA waves0-1 (R16) -> uu LDS
//   -> u_hat (fixed-dp, W 2-deep prefetch) -> uhh LDS (aliases sOut)
//   -> 3 routing iters (R15 phase code) -> pred, v.
//   LDS unions: {sIn,sW} ~ {blog,cc};  sOut ~ uhh.  u never touches HBM.

typedef _Float16 half2_t __attribute__((ext_vector_type(2)));
typedef _Float16 f16x4 __attribute__((ext_vector_type(4)));
typedef _Float16 f16x8 __attribute__((ext_vector_type(8)));
typedef float f32x16 __attribute__((ext_vector_type(16)));

static __device__ __forceinline__ float fdot2f(half2_t a, half2_t b, float c) {
#if __has_builtin(__builtin_amdgcn_fdot2)
  return __builtin_amdgcn_fdot2(a, b, c, false);
#else
  return c + (float)a[0] * (float)b[0] + (float)a[1] * (float)b[1];
#endif
}

static __device__ __forceinline__ half2_t h2(unsigned int u) {
  return __builtin_bit_cast(half2_t, u);
}

static __device__ __forceinline__ unsigned int pkh2(float a, float b) {
  half2_t h;
  h[0] = (_Float16)a;
  h[1] = (_Float16)b;
  return __builtin_bit_cast(unsigned int, h);
}

static __device__ __forceinline__ f32x16 zero16() {
  f32x16 z = {0.f, 0.f, 0.f, 0.f, 0.f, 0.f, 0.f, 0.f,
              0.f, 0.f, 0.f, 0.f, 0.f, 0.f, 0.f, 0.f};
  return z;
}

// Fused packs. idx < 92160: W_route -> wPr f16 c-pairs.
//              idx < 41472: w2 -> wBg MFMA B-fragments.
__global__ __launch_bounds__(256) void packAll(
    const float* __restrict__ w2, const float* __restrict__ Wr,
    _Float16* __restrict__ wBg, unsigned int* __restrict__ wPr) {
  int idx = blockIdx.x * 256 + threadIdx.x;
  if (idx < 92160) {
    int cp = idx & 3;
    int row = idx >> 2;
    const float* src = Wr + (size_t)row * 8 + cp * 2;
    wPr[idx] = pkh2(src[0], src[1]);
  }
  if (idx < 41472) {
    int j = idx & 7;
    int lane = (idx >> 3) & 63;
    int step = idx >> 9;
    int kh = step / 9, kw = step - kh * 9;
    int co = lane & 31, ci = (lane >> 5) * 8 + j;
    wBg[idx] = (_Float16)w2[(co * 16 + ci) * 81 + kh * 9 + kw];
  }
}

// LDS map (byte offsets into smem[65216]):
//   [0,8320)      sIn 784 f32 | sW 1296 f32      (die after conv1)
//   [0,11520)     blog 1440 f32 | cc 1440 f32    (born after conv1)
//   [11520,58752) sOut [400][20] f16 (16000B, dies after conv2)
//                 uhh 144x(stride 82) u32 (47232B, born in u_hat)
//   [58752,61056) uu [144][8] f16
//   [61056,63616) spart [4][160] f32
//   [63616,64256) ss 160 f32
//   [64256,64896) vv 160 f32
//   [64896,65216) vvh 80 u32
__global__ __launch_bounds__(320) void capsnet_fused(
    const float* __restrict__ in, const float* __restrict__ w1g,
    const float* __restrict__ bias1, const _Float16* __restrict__ wBg,
    const float* __restrict__ bias2, const unsigned int* __restrict__ wPr,
    float* __restrict__ out, int B) {
  __shared__ __align__(16) unsigned char smem[65216];
  float* sIn = (float*)smem;                           // 784
  float* sW = (float*)(smem + 3136);                   // 1296
  float* blog = (float*)smem;                          // 1440
  float* cc = (float*)(smem + 5760);                   // 1440
  _Float16* sOut = (_Float16*)(smem + 11520);          // [400][20]
  unsigned int* uhh = (unsigned int*)(smem + 11520);   // [i*82+dp]
  _Float16* uu = (_Float16*)(smem + 58752);            // [144][8]
  float* spart = (float*)(smem + 61056);               // [4][160]
  float* ss = (float*)(smem + 63616);                  // 160
  float* vv = (float*)(smem + 64256);                  // 160
  unsigned int* vvh = (unsigned int*)(smem + 64896);   // 80

  int b = blockIdx.x, t = threadIdx.x;
  const float* inb = in + b * 784;
  for (int i = t; i < 784; i += 320) sIn[i] = inb[i];
  for (int i = t; i < 1296; i += 320) sW[i] = w1g[i];
  __syncthreads();

  // ---- conv1 (R16 proven): fp32, 320 work items = (co, oh) ----
  {
    int co = t / 20, oh = t % 20;
    float bv = bias1[co];
    float acc[20];
#pragma unroll
    for (int j = 0; j < 20; ++j) acc[j] = bv;
#pragma unroll
    for (int kh = 0; kh < 9; ++kh) {
      float r[28];
      const float4* row = (const float4*)&sIn[(oh + kh) * 28];
#pragma unroll
      for (int q = 0; q < 7; ++q) {
        float4 v = row[q];
        r[q * 4 + 0] = v.x; r[q * 4 + 1] = v.y;
        r[q * 4 + 2] = v.z; r[q * 4 + 3] = v.w;
      }
      const float* wr = &sW[co * 81 + kh * 9];
#pragma unroll
      for (int kw = 0; kw < 9; ++kw) {
        float wv = wr[kw];
#pragma unroll
        for (int j = 0; j < 20; ++j) acc[j] += wv * r[kw + j];
      }
    }
#pragma unroll
    for (int j = 0; j < 20; ++j) sOut[(oh * 20 + j) * 20 + co] = (_Float16)acc[j];
  }
  __syncthreads();   // sIn/sW dead; sOut live

  // ---- conv2 MFMA (waves 0-1, R16 proven) -> uu f16; waves 2-4 zero blog ----
  int wv = t >> 6, lane = t & 63;
  if (wv < 2) {
    int l31 = lane & 31, half = lane >> 5;
    int r = wv * 32 + l31;
    int rc = (r < 36) ? r : 35;
    int oh = rc / 6, ow = rc - oh * 6;
    int tb = (oh * 40 + ow * 2) * 20 + half * 8;
    f32x16 acc = zero16();
    for (int kh = 0; kh < 9; ++kh) {
      int abase = tb + kh * 400;
#pragma unroll
      for (int kw = 0; kw < 9; ++kw) {
        f16x8 bf = *(const f16x8*)(wBg + ((kh * 9 + kw) * 64 + lane) * 8);
        const _Float16* ap = sOut + abase + kw * 20;
        f16x4 lo = *(const f16x4*)ap;
        f16x4 hi = *(const f16x4*)(ap + 4);
        f16x8 a = __builtin_shufflevector(lo, hi, 0, 1, 2, 3, 4, 5, 6, 7);
        acc = __builtin_amdgcn_mfma_f32_32x32x16_f16(a, bf, acc, 0, 0, 0);
      }
    }
    float bv = bias2[l31];
    int c8 = l31 >> 2;
    int ibco = (l31 & 3) * 36;
#pragma unroll
    for (int reg = 0; reg < 16; ++reg) {
      int rr = wv * 32 + (reg & 3) + 8 * (reg >> 2) + 4 * half;
      if (rr < 36) uu[(ibco + rr) * 8 + c8] = (_Float16)(acc[reg] + bv);
    }
  } else {
    for (int j = t - 128; j < 1440; j += 192) blog[j] = 0.f;
  }
  __syncthreads();   // sOut dead; uu, blog live

  // ---- u_hat: fixed dp per thread (320 = 4*80), i = t/80 + 4e, W prefetch ----
  {
    const uint4* W4 = (const uint4*)wPr;   // rows [i*160 + o*16 + d] of 8 f16
    int i0 = t / 80, dp = t - (t / 80) * 80;
    int rowoff = (dp >> 3) * 16 + (dp & 7) * 2;
    uint4 w0a = W4[i0 * 160 + rowoff];
    uint4 w1a = W4[i0 * 160 + rowoff + 1];
    for (int e = 0; e < 36; ++e) {
      int i = i0 + 4 * e;
      uint4 w0b, w1b;
      if (e < 35) {
        int nr = (i + 4) * 160 + rowoff;
        w0b = W4[nr];
        w1b = W4[nr + 1];
      }
      const unsigned int* uup = (const unsigned int*)(uu + i * 8);
      unsigned int x0 = uup[0], x1 = uup[1], x2 = uup[2], x3 = uup[3];
      float a0 = fdot2f(h2(w0a.x), h2(x0),
                 fdot2f(h2(w0a.y), h2(x1),
                 fdot2f(h2(w0a.z), h2(x2), fdot2f(h2(w0a.w), h2(x3), 0.f))));
      float a1 = fdot2f(h2(w1a.x), h2(x0),
                 fdot2f(h2(w1a.y), h2(x1),
                 fdot2f(h2(w1a.z), h2(x2), fdot2f(h2(w1a.w), h2(x3), 0.f))));
      uhh[i * 82 + dp] = pkh2(a0, a1);
      w0a = w0b;
      w1a = w1b;
    }
  }
  __syncthreads();

  // ---- routing iterations (R15-proven phase code, 320 threads) ----
  for (int it = 0; it < 3; ++it) {
    if (it > 0) {
      if (t < 144) {
        const float* br = &blog[t * 10];
        float mx = br[0];
#pragma unroll
        for (int o = 1; o < 10; ++o) mx = fmaxf(mx, br[o]);
        float e[10];
        float sum = 0.f;
#pragma unroll
        for (int o = 0; o < 10; ++o) { e[o] = __expf(br[o] - mx); sum += e[o]; }
        float inv = 1.0f / sum;
#pragma unroll
        for (int o = 0; o < 10; ++o) cc[t * 10 + o] = e[o] * inv;
      }
      __syncthreads();
    }
    // s partials: 320 lanes = 4 i-chunks x 80 d-pairs (36 i each)
    {
      int ch = t / 80, dp = t - (t / 80) * 80;
      int o = dp >> 3;
      int i0c = ch * 36;
      float a0 = 0.f, a1 = 0.f;
      if (it == 0) {
        for (int i = i0c; i < i0c + 36; ++i) {
          half2_t h = h2(uhh[i * 82 + dp]);
          a0 += (float)h[0]; a1 += (float)h[1];
        }
      } else {
        for (int i = i0c; i < i0c + 36; ++i) {
          float c = cc[i * 10 + o];
          half2_t h = h2(uhh[i * 82 + dp]);
          a0 += c * (float)h[0]; a1 += c * (float)h[1];
        }
      }
      spart[ch * 160 + dp * 2] = a0;
      spart[ch * 160 + dp * 2 + 1] = a1;
    }
    __syncthreads();
    if (t < 160) {
      float s = spart[t] + spart[160 + t] + spart[320 + t] + spart[480 + t];
      ss[t] = (it == 0) ? s * 0.1f : s;   // it==0: softmax of zeros = 0.1
    }
    __syncthreads();
    if (t < 10) {
      float sq = 0.f;
#pragma unroll
      for (int d = 0; d < 16; ++d) { float x = ss[t * 16 + d]; sq += x * x; }
      float coef = (sq / (1.0f + sq)) / sqrtf(sq + 1e-8f);
#pragma unroll
      for (int q = 0; q < 8; ++q) {
        float v0 = coef * ss[t * 16 + 2 * q];
        float v1 = coef * ss[t * 16 + 2 * q + 1];
        vv[t * 16 + 2 * q] = v0;
        vv[t * 16 + 2 * q + 1] = v1;
        vvh[t * 8 + q] = pkh2(v0, v1);
      }
      if (it == 2) out[b * 10 + t] = coef * sqrtf(sq);   // pred = ||v||
    }
    __syncthreads();
    if (it < 2) {
      for (int idx = t; idx < 1440; idx += 320) {
        int i = idx / 10, o = idx - i * 10;
        const uint2* uhp = (const uint2*)&uhh[i * 82 + o * 8];
        const uint2* vp = (const uint2*)&vvh[o * 8];
        float dot = 0.f;
#pragma unroll
        for (int q = 0; q < 4; ++q) {
          uint2 A = uhp[q], V = vp[q];
          dot = fdot2f(h2(A.x), h2(V.x), fdot2f(h2(A.y), h2(V.y), dot));
        }
        blog[idx] += dot;
      }
      __syncthreads();
    }
  }
  if (t < 160) out[B * 10 + b * 160 + t] = vv[t];
}

extern "C" void kernel_launch(void* const* d_in, const int* in_sizes, int n_in,
                              void* d_out, int out_size, void* d_ws, size_t ws_size,
                              hipStream_t stream) {
  const float* in = (const float*)d_in[0];
  const float* w1 = (const float*)d_in[1];
  const float* b1 = (const float*)d_in[2];
  const float* w2 = (const float*)d_in[3];
  const float* b2 = (const float*)d_in[4];
  const float* Wr = (const float*)d_in[5];
  float* out = (float*)d_out;
  int B = in_sizes[0] / 784;
  float* wsf = (float*)d_ws;

  _Float16* wBg = (_Float16*)wsf;                      // 41472 f16 = 20736 f
  unsigned int* wPr = (unsigned int*)(wsf + 20736);    // 92160 dw

  packAll<<<360, 256, 0, stream>>>(w2, Wr, wBg, wPr);
  capsnet_fused<<<B, 320, 0, stream>>>(in, w1, b1, wBg, b2, wPr, out, B);
}